// Round 2
// baseline (27659.085 us; speedup 1.0000x reference)
//
#include <hip/hip_runtime.h>
#include <hip/hip_bf16.h>
#include <math.h>

// ---- problem constants ----
#define V    32000
#define E    512
#define NH   8
#define DH   64
#define NL   2
#define FF   2048
#define MAXLEN 24
#define S    48
#define B    8
#define TRANS 14
#define INIT 12      // TRANS - 2
#define LF   35      // INIT + MAXLEN - 1

#define NB   256     // persistent grid blocks (== CU count, co-resident)
#define NT   512     // threads per block (8 waves)
#define NWAVE (NB * (NT / 64))   // 2048 waves

__device__ inline float wsum(float v) {
#pragma unroll
  for (int off = 32; off; off >>= 1) v += __shfl_xor(v, off);
  return v;
}
__device__ inline float wmax(float v) {
#pragma unroll
  for (int off = 32; off; off >>= 1) v = fmaxf(v, __shfl_xor(v, off));
  return v;
}

// ================= prefill kernels (round-1, unchanged semantics) =================

__global__ void embed_init_k(const int* __restrict__ transform, const float* __restrict__ emb,
                             float* __restrict__ xbuf) {
  int t = blockIdx.x;          // 0..INIT*B-1, pos-major
  int pos = t >> 3, b = t & 7;
  int tok = transform[(1 + pos) * B + b];
  for (int d = threadIdx.x; d < E; d += blockDim.x) {
    double div = exp(-log(10000.0) * (double)(d & ~1) / (double)E);
    double ang = (double)pos * div;
    float pe = (d & 1) ? (float)cos(ang) : (float)sin(ang);
    xbuf[(size_t)t * E + d] = emb[(size_t)tok * E + d] + pe;
  }
}

template <int K>
__global__ __launch_bounds__(256) void gemm_k(
    const float* __restrict__ x, const float* __restrict__ W, const float* __restrict__ bias,
    int ntok, int nout, int route, int relu,
    float* __restrict__ out0, float* __restrict__ out1, float* __restrict__ out2) {
  constexpr int K4 = K / 4;
  constexpr int J  = K / 256;
  __shared__ float4 xt[8][K4];
  const int tid = threadIdx.x;
  const int lane = tid & 63;
  const int o = blockIdx.x * 4 + (tid >> 6);

  float4 wr[J];
  if (o < nout) {
    const float4* Wr = (const float4*)(W + (size_t)o * K);
#pragma unroll
    for (int j = 0; j < J; ++j) wr[j] = Wr[lane + 64 * j];
  }

  const int ng = ntok >> 3;
  for (int g = 0; g < ng; ++g) {
    if (g) __syncthreads();
    const float4* xg = (const float4*)(x + (size_t)g * 8 * K);
    float4* xf = &xt[0][0];
    for (int i = tid; i < 8 * K4; i += 256) xf[i] = xg[i];
    __syncthreads();
    if (o < nout) {
      float acc[8] = {0, 0, 0, 0, 0, 0, 0, 0};
#pragma unroll
      for (int j = 0; j < J; ++j) {
        float4 w = wr[j];
#pragma unroll
        for (int tt = 0; tt < 8; ++tt) {
          float4 xv = xt[tt][lane + 64 * j];
          acc[tt] += w.x * xv.x + w.y * xv.y + w.z * xv.z + w.w * xv.w;
        }
      }
#pragma unroll
      for (int tt = 0; tt < 8; ++tt) acc[tt] = wsum(acc[tt]);
      if (lane == 0) {
        float bo = bias[o];
#pragma unroll
        for (int tt = 0; tt < 8; ++tt) {
          float v = acc[tt] + bo;
          if (relu) v = fmaxf(v, 0.f);
          int t = g * 8 + tt;
          if (route == 0) {
            out0[(size_t)t * nout + o] = v;
          } else if (route == 1) {
            if (o < E) out0[(size_t)t * E + o] = v;
            else if (o < 2 * E) out1[(size_t)t * E + (o - E)] = v;
            else out2[(size_t)t * E + (o - 2 * E)] = v;
          } else {
            if (o < E) out0[(size_t)t * E + o] = v;
            else out1[(size_t)t * E + (o - E)] = v;
          }
        }
      }
    }
  }
}

__global__ __launch_bounds__(256) void attn_k(
    const float* __restrict__ q, const float* __restrict__ Kc, const float* __restrict__ Vc,
    float* __restrict__ outp, int p0, int nq, int nk_fixed, int causal) {
  const int tid = threadIdx.x;
  const int lane = tid & 63;
  const int u = blockIdx.x * 4 + (tid >> 6);
  if (u >= nq * 64) return;
  const int qi = u >> 6;
  const int r = u & 63;
  const int b = r >> 3, h = r & 7;
  const int nk = causal ? (p0 + qi + 1) : nk_fixed;

  const size_t qoff = (size_t)(qi * B + b) * E + h * DH + lane;
  const float qv = q[qoff];

  float myscore = -INFINITY;
  for (int k = 0; k < nk; ++k) {
    float prod = qv * Kc[(size_t)(k * B + b) * E + h * DH + lane];
    prod = wsum(prod);
    if (lane == k) myscore = prod * 0.125f;
  }
  float m = wmax(myscore);
  float p = (lane < nk) ? expf(myscore - m) : 0.f;
  float denom = wsum(p);
  float a = p / denom;

  float oacc = 0.f;
  for (int k = 0; k < nk; ++k) {
    float ak = __shfl(a, k);
    oacc = fmaf(ak, Vc[(size_t)(k * B + b) * E + h * DH + lane], oacc);
  }
  outp[qoff] = oacc;
}

__global__ __launch_bounds__(256) void add_ln_k(
    const float* __restrict__ xa, const float* __restrict__ xb,
    const float* __restrict__ g, const float* __restrict__ beta,
    float* __restrict__ outp, int ntok) {
  const int tid = threadIdx.x, lane = tid & 63;
  const int t = blockIdx.x * 4 + (tid >> 6);
  if (t >= ntok) return;
  float v[8];
  float s = 0.f;
#pragma unroll
  for (int j = 0; j < 8; ++j) {
    int d = lane + 64 * j;
    v[j] = xa[(size_t)t * E + d] + xb[(size_t)t * E + d];
    s += v[j];
  }
  s = wsum(s);
  float mean = s * (1.f / 512.f);
  float d2 = 0.f;
#pragma unroll
  for (int j = 0; j < 8; ++j) { float dd = v[j] - mean; d2 += dd * dd; }
  d2 = wsum(d2);
  float inv = 1.f / sqrtf(d2 * (1.f / 512.f) + 1e-5f);
#pragma unroll
  for (int j = 0; j < 8; ++j) {
    int d = lane + 64 * j;
    outp[(size_t)t * E + d] = (v[j] - mean) * inv * g[d] + beta[d];
  }
}

// ================= persistent autoregressive decode kernel =================
// grid = NB(256) blocks x NT(512) threads; all co-resident; custom grid barrier.

__global__ __launch_bounds__(NT, 1) void decode_persist_k(
    const float* __restrict__ emb,
    const float* __restrict__ sa_w, const float* __restrict__ sa_b,
    const float* __restrict__ sa_ow, const float* __restrict__ sa_ob,
    const float* __restrict__ ca_w, const float* __restrict__ ca_b,
    const float* __restrict__ ca_ow, const float* __restrict__ ca_ob,
    const float* __restrict__ ff1_w, const float* __restrict__ ff1_b,
    const float* __restrict__ ff2_w, const float* __restrict__ ff2_b,
    const float* __restrict__ ln_g, const float* __restrict__ ln_b,
    const float* __restrict__ out_w, const float* __restrict__ out_b,
    float* __restrict__ kself, float* __restrict__ vself,
    const float* __restrict__ kcross, const float* __restrict__ vcross,
    float* __restrict__ qbuf, float* __restrict__ attnout, float* __restrict__ gout,
    float* __restrict__ xlbuf, float* __restrict__ x1buf, float* __restrict__ x2buf,
    float* __restrict__ xstep, float* __restrict__ ffdec,
    float* __restrict__ outp, int* __restrict__ bar) {
  __shared__ float s_x[8 * FF];        // 64 KB staging tile (max: ff2 K=2048)
  __shared__ float s_red[NT];
  __shared__ int   s_idx[NT];

  const int tid  = threadIdx.x;
  const int lane = tid & 63;
  const int wv   = tid >> 6;                 // wave in block (0..7)
  const int wid  = blockIdx.x * (NT / 64) + wv;
  const size_t SELF_SZ  = (size_t)LF * B * E;
  const size_t CROSS_SZ = (size_t)S * B * E;
  int bt = 0;                                // barrier generation

  // ---- grid barrier: sense-free monotonic generation ----
  auto bar_sync = [&]() {
    ++bt;
    __syncthreads();
    if (tid == 0) {
      int old = __hip_atomic_fetch_add(&bar[0], 1, __ATOMIC_ACQ_REL, __HIP_MEMORY_SCOPE_AGENT);
      if (old == bt * NB - 1) {
        __hip_atomic_store(&bar[1], bt, __ATOMIC_RELEASE, __HIP_MEMORY_SCOPE_AGENT);
      } else {
        while (__hip_atomic_load(&bar[1], __ATOMIC_ACQUIRE, __HIP_MEMORY_SCOPE_AGENT) < bt)
          __builtin_amdgcn_s_sleep(2);
      }
    }
    __syncthreads();
  };

  // ---- stage helpers (x tile [8][K] -> LDS) ----
  auto stage_copy = [&](const float* src, int nflt) {
    const float4* s4 = (const float4*)src;
    float4* d4 = (float4*)s_x;
    for (int i = tid; i < nflt / 4; i += NT) d4[i] = s4[i];
    __syncthreads();
  };
  // x = LN(xa + xb) * g + be ; wave wv handles token wv; optionally materialize to wout
  auto stage_ln = [&](const float* xa, const float* xb, const float* g, const float* be,
                      float* wout) {
    float v[8];
    float s = 0.f;
#pragma unroll
    for (int j = 0; j < 8; ++j) {
      int d = lane + 64 * j;
      v[j] = xa[wv * E + d] + xb[wv * E + d];
      s += v[j];
    }
    s = wsum(s);
    float mean = s * (1.f / 512.f);
    float d2 = 0.f;
#pragma unroll
    for (int j = 0; j < 8; ++j) { float dd = v[j] - mean; d2 += dd * dd; }
    d2 = wsum(d2);
    float inv = 1.f / sqrtf(d2 * (1.f / 512.f) + 1e-5f);
#pragma unroll
    for (int j = 0; j < 8; ++j) {
      int d = lane + 64 * j;
      float nv = (v[j] - mean) * inv * g[d] + be[d];
      s_x[wv * E + d] = nv;
      if (wout && blockIdx.x == 0) wout[wv * E + d] = nv;
    }
    __syncthreads();
  };

  // ---- GEMM over staged tile: out[t,o] = act(sum sx[t,:]*W[o,:] + b[o]) ----
  // route 0: o0[t*nout+o]; route 1 (QKV): o<E->qbuf, <2E->kdst, else vdst (stride E)
  auto gemm = [&](int K, const float* W, const float* bias, int nout, int relu, int route,
                  float* o0, float* kdst, float* vdst) {
    const float4* sx4 = (const float4*)s_x;
    const int K4 = K / 4;
    const int NJ = K / 256;
    for (int o = wid; o < nout; o += NWAVE) {
      const float4* Wr = (const float4*)(W + (size_t)o * K);
      float acc[8] = {0, 0, 0, 0, 0, 0, 0, 0};
      for (int jj = 0; jj < NJ; ++jj) {
        float4 w = Wr[lane + 64 * jj];
#pragma unroll
        for (int t = 0; t < 8; ++t) {
          float4 xv = sx4[t * K4 + lane + 64 * jj];
          acc[t] += w.x * xv.x + w.y * xv.y + w.z * xv.z + w.w * xv.w;
        }
      }
#pragma unroll
      for (int t = 0; t < 8; ++t) acc[t] = wsum(acc[t]);
      if (lane == 0) {
        float bo = bias[o];
#pragma unroll
        for (int t = 0; t < 8; ++t) {
          float vv = acc[t] + bo;
          if (relu) vv = fmaxf(vv, 0.f);
          if (route == 0) o0[(size_t)t * nout + o] = vv;
          else {
            if (o < E) o0[t * E + o] = vv;
            else if (o < 2 * E) kdst[t * E + (o - E)] = vv;
            else vdst[t * E + (o - 2 * E)] = vv;
          }
        }
      }
    }
  };

  // ---- attention (blocks 0..7 = batch, wave = head, lane = dim) ----
  auto attn = [&](const float* Kc, const float* Vc, int nk) {
    if (blockIdx.x < 8) {
      const int b = blockIdx.x, h = wv;
      const float qv = qbuf[b * E + h * DH + lane];
      float sc = -INFINITY;
      for (int k = 0; k < nk; ++k) {
        float pr = wsum(qv * Kc[(size_t)(k * B + b) * E + h * DH + lane]);
        if (lane == k) sc = pr * 0.125f;
      }
      float m = wmax(sc);
      float pv = (lane < nk) ? expf(sc - m) : 0.f;
      float den = wsum(pv);
      float a = pv / den;
      float oa = 0.f;
      for (int k = 0; k < nk; ++k) {
        float ak = __shfl(a, k);
        oa = fmaf(ak, Vc[(size_t)(k * B + b) * E + h * DH + lane], oa);
      }
      attnout[b * E + h * DH + lane] = oa;
    }
  };

  // ================= 23 autoregressive steps =================
  for (int i = 0; i < MAXLEN - 1; ++i) {
    const int p = INIT + i;                    // position being decoded (12..34)

    // stage 0: argmax of logits row p-1 (per batch) + re-embed at PE position 0
    if (blockIdx.x < 8) {
      const float* row = outp + ((size_t)(p - 1) * B + blockIdx.x) * V;
      float bv = -INFINITY; int bi = 0x7fffffff;
      for (int j = tid; j < V; j += NT) {
        float vv = row[j];
        if (vv > bv || (vv == bv && j < bi)) { bv = vv; bi = j; }
      }
      s_red[tid] = bv; s_idx[tid] = bi;
      __syncthreads();
      for (int s = NT / 2; s; s >>= 1) {
        if (tid < s) {
          float ov = s_red[tid + s]; int oi = s_idx[tid + s];
          if (ov > s_red[tid] || (ov == s_red[tid] && oi < s_idx[tid])) {
            s_red[tid] = ov; s_idx[tid] = oi;
          }
        }
        __syncthreads();
      }
      const int tok = s_idx[0];
      for (int d = tid; d < E; d += NT)
        xstep[blockIdx.x * E + d] = emb[(size_t)tok * E + d] + ((d & 1) ? 1.0f : 0.0f);
    }
    bar_sync();

    for (int l = 0; l < NL; ++l) {
      // S1: QKV projection (layer input staged; for l=1 fuse layer-0 final LN)
      if (l == 0) stage_copy(xstep, 8 * E);
      else        stage_ln(x2buf, gout, ln_g + 2 * E, ln_b + 2 * E, xlbuf);  // ln[0,2]
      gemm(E, sa_w + (size_t)l * 3 * E * E, sa_b + (size_t)l * 3 * E, 3 * E, 0, 1,
           qbuf, kself + l * SELF_SZ + (size_t)p * B * E, vself + l * SELF_SZ + (size_t)p * B * E);
      bar_sync();
      // S2: self-attention (keys 0..p)
      attn(kself + l * SELF_SZ, vself + l * SELF_SZ, p + 1);
      bar_sync();
      // S3: self-attn output projection
      stage_copy(attnout, 8 * E);
      gemm(E, sa_ow + (size_t)l * E * E, sa_ob + (size_t)l * E, E, 0, 0, gout, 0, 0);
      bar_sync();
      // S4: x1 = LN(x_layer + sa_out) [ln l,0]; cross-attn Q projection
      stage_ln((l == 0) ? xstep : xlbuf, gout,
               ln_g + ((size_t)l * 3 + 0) * E, ln_b + ((size_t)l * 3 + 0) * E, x1buf);
      gemm(E, ca_w + (size_t)l * 3 * E * E, ca_b + (size_t)l * 3 * E, E, 0, 0, qbuf, 0, 0);
      bar_sync();
      // S5: cross-attention (48 encoder keys)
      attn(kcross + l * CROSS_SZ, vcross + l * CROSS_SZ, S);
      bar_sync();
      // S6: cross-attn output projection
      stage_copy(attnout, 8 * E);
      gemm(E, ca_ow + (size_t)l * E * E, ca_ob + (size_t)l * E, E, 0, 0, gout, 0, 0);
      bar_sync();
      // S7: x2 = LN(x1 + ca_out) [ln l,1]; FFN-1 (ReLU)
      stage_ln(x1buf, gout, ln_g + ((size_t)l * 3 + 1) * E, ln_b + ((size_t)l * 3 + 1) * E, x2buf);
      gemm(E, ff1_w + (size_t)l * FF * E, ff1_b + (size_t)l * FF, FF, 1, 0, ffdec, 0, 0);
      bar_sync();
      // S8: FFN-2
      stage_copy(ffdec, 8 * FF);
      gemm(FF, ff2_w + (size_t)l * E * FF, ff2_b + (size_t)l * E, E, 0, 0, gout, 0, 0);
      bar_sync();
    }
    // logits: x3 = LN(x2 + ff_out) [ln 1,2] -> output projection into final rows
    stage_ln(x2buf, gout, ln_g + (3 + 2) * E, ln_b + (3 + 2) * E, nullptr);
    gemm(E, out_w, out_b, V, 0, 0, outp + (size_t)p * B * V, 0, 0);
    bar_sync();
  }
}

extern "C" void kernel_launch(void* const* d_in, const int* in_sizes, int n_in,
                              void* d_out, int out_size, void* d_ws, size_t ws_size,
                              hipStream_t stream) {
  const float* enc       = (const float*)d_in[0];
  const int*   transform = (const int*)d_in[1];
  const float* emb       = (const float*)d_in[3];
  const float* sa_w  = (const float*)d_in[4];
  const float* sa_b  = (const float*)d_in[5];
  const float* sa_ow = (const float*)d_in[6];
  const float* sa_ob = (const float*)d_in[7];
  const float* ca_w  = (const float*)d_in[8];
  const float* ca_b  = (const float*)d_in[9];
  const float* ca_ow = (const float*)d_in[10];
  const float* ca_ob = (const float*)d_in[11];
  const float* ff1_w = (const float*)d_in[12];
  const float* ff1_b = (const float*)d_in[13];
  const float* ff2_w = (const float*)d_in[14];
  const float* ff2_b = (const float*)d_in[15];
  const float* ln_g  = (const float*)d_in[16];
  const float* ln_b  = (const float*)d_in[17];
  const float* out_w = (const float*)d_in[18];
  const float* out_b = (const float*)d_in[19];
  float* out = (float*)d_out;

  // workspace layout (floats)
  const size_t SELF_SZ  = (size_t)LF * B * E;    // 143360
  const size_t CROSS_SZ = (size_t)S * B * E;     // 196608
  float* ws     = (float*)d_ws;
  float* xbuf   = ws;                            // 12 prefill positions only
  float* kself  = xbuf + (size_t)INIT * B * E;   // 49152
  float* vself  = kself + NL * SELF_SZ;
  float* kcross = vself + NL * SELF_SZ;
  float* vcross = kcross + NL * CROSS_SZ;
  float* act0   = vcross + NL * CROSS_SZ;        // [96,E]
  float* act1   = act0 + 96 * E;
  float* act2   = act1 + 96 * E;
  float* act3   = act2 + 96 * E;
  float* ffb    = act3 + 96 * E;                 // [96,FF]
  int*   bar    = (int*)(ffb + 96 * FF);         // 2 ints, beyond all prefill use

  hipMemsetAsync(bar, 0, 256, stream);

  // 1) initial embeddings (positions 0..11)
  embed_init_k<<<INIT * B, 128, 0, stream>>>(transform, emb, xbuf);

  // 2) cross-attn K/V caches
  for (int l = 0; l < NL; ++l) {
    gemm_k<E><<<(2 * E) / 4, 256, 0, stream>>>(
        enc, ca_w + ((size_t)l * 3 * E + E) * E, ca_b + (size_t)l * 3 * E + E,
        S * B, 2 * E, 2, 0, kcross + l * CROSS_SZ, vcross + l * CROSS_SZ, nullptr);
  }

  // 3) prefill positions 0..11 via round-1 kernels (one-time)
  {
    const int p0 = 0, nq = INIT, ntok = nq * B;
    const float* xin = xbuf;
    for (int l = 0; l < NL; ++l) {
      const float* x = (l == 0) ? xin : act0;
      gemm_k<E><<<(3 * E) / 4, 256, 0, stream>>>(
          x, sa_w + (size_t)l * 3 * E * E, sa_b + (size_t)l * 3 * E, ntok, 3 * E, 1, 0,
          act1, kself + l * SELF_SZ, vself + l * SELF_SZ);
      attn_k<<<nq * 16, 256, 0, stream>>>(act1, kself + l * SELF_SZ, vself + l * SELF_SZ,
                                          act2, p0, nq, 0, 1);
      gemm_k<E><<<E / 4, 256, 0, stream>>>(
          act2, sa_ow + (size_t)l * E * E, sa_ob + (size_t)l * E, ntok, E, 0, 0, act3, nullptr, nullptr);
      add_ln_k<<<(ntok + 3) / 4, 256, 0, stream>>>(
          x, act3, ln_g + (size_t)l * 3 * E, ln_b + (size_t)l * 3 * E, act0, ntok);
      gemm_k<E><<<E / 4, 256, 0, stream>>>(
          act0, ca_w + (size_t)l * 3 * E * E, ca_b + (size_t)l * 3 * E, ntok, E, 0, 0, act1, nullptr, nullptr);
      attn_k<<<nq * 16, 256, 0, stream>>>(act1, kcross + l * CROSS_SZ, vcross + l * CROSS_SZ,
                                          act2, p0, nq, S, 0);
      gemm_k<E><<<E / 4, 256, 0, stream>>>(
          act2, ca_ow + (size_t)l * E * E, ca_ob + (size_t)l * E, ntok, E, 0, 0, act3, nullptr, nullptr);
      add_ln_k<<<(ntok + 3) / 4, 256, 0, stream>>>(
          act0, act3, ln_g + (size_t)l * 3 * E + E, ln_b + (size_t)l * 3 * E + E, act0, ntok);
      gemm_k<E><<<FF / 4, 256, 0, stream>>>(
          act0, ff1_w + (size_t)l * FF * E, ff1_b + (size_t)l * FF, ntok, FF, 0, 1, ffb, nullptr, nullptr);
      gemm_k<FF><<<E / 4, 256, 0, stream>>>(
          ffb, ff2_w + (size_t)l * E * FF, ff2_b + (size_t)l * E, ntok, E, 0, 0, act3, nullptr, nullptr);
      add_ln_k<<<(ntok + 3) / 4, 256, 0, stream>>>(
          act0, act3, ln_g + (size_t)l * 3 * E + 2 * E, ln_b + (size_t)l * 3 * E + 2 * E, act0, ntok);
    }
    gemm_k<E><<<V / 4, 256, 0, stream>>>(
        act0, out_w, out_b, ntok, V, 0, 0, out, nullptr, nullptr);
  }

  // 4) persistent kernel: all 23 autoregressive steps
  float* qbuf    = act1;
  float* attnout = act2;
  float* gout    = act3;
  float* xlbuf   = act0;
  float* x1buf   = act0 + 8 * E;
  float* x2buf   = act0 + 16 * E;
  float* xstep   = act0 + 24 * E;
  float* ffdec   = ffb;            // [8,2048]
  decode_persist_k<<<NB, NT, 0, stream>>>(
      emb, sa_w, sa_b, sa_ow, sa_ob, ca_w, ca_b, ca_ow, ca_ob,
      ff1_w, ff1_b, ff2_w, ff2_b, ln_g, ln_b, out_w, out_b,
      kself, vself, kcross, vcross,
      qbuf, attnout, gout, xlbuf, x1buf, x2buf, xstep, ffdec,
      out, bar);
}

// Round 3
// 6123.582 us; speedup vs baseline: 4.5168x; 4.5168x over previous
//
#include <hip/hip_runtime.h>
#include <hip/hip_bf16.h>
#include <math.h>

// ---- problem constants ----
#define V    32000
#define E    512
#define NH   8
#define DH   64
#define NL   2
#define FF   2048
#define MAXLEN 24
#define S    48
#define B    8
#define TRANS 14
#define INIT 12      // TRANS - 2
#define LF   35      // INIT + MAXLEN - 1

#define NB   256     // persistent grid blocks (== CU count, co-resident)
#define NT   512     // threads per block (8 waves)
#define NWAVE (NB * (NT / 64))   // 2048 waves

__device__ inline float wsum(float v) {
#pragma unroll
  for (int off = 32; off; off >>= 1) v += __shfl_xor(v, off);
  return v;
}

// ---- coherence-point (MALL) load/store helpers: relaxed agent atomics.
// NO cache maintenance instructions are emitted (that was round-2's 64us/barrier bug);
// these simply bypass the non-coherent L1/L2 path for reused activation buffers.
__device__ inline float ldc(const float* p) {
  return __hip_atomic_load(p, __ATOMIC_RELAXED, __HIP_MEMORY_SCOPE_AGENT);
}
__device__ inline void stc(float* p, float v) {
  __hip_atomic_store(p, v, __ATOMIC_RELAXED, __HIP_MEMORY_SCOPE_AGENT);
}
__device__ inline float2 ldc8(const float* p) {
  union { unsigned long long u; float2 f; } c;
  c.u = __hip_atomic_load((const unsigned long long*)p, __ATOMIC_RELAXED, __HIP_MEMORY_SCOPE_AGENT);
  return c.f;
}

// ================= prefill kernels (round-1, proven) =================

__global__ void embed_init_k(const int* __restrict__ transform, const float* __restrict__ emb,
                             float* __restrict__ xbuf) {
  int t = blockIdx.x;
  int pos = t >> 3, b = t & 7;
  int tok = transform[(1 + pos) * B + b];
  for (int d = threadIdx.x; d < E; d += blockDim.x) {
    double div = exp(-log(10000.0) * (double)(d & ~1) / (double)E);
    double ang = (double)pos * div;
    float pe = (d & 1) ? (float)cos(ang) : (float)sin(ang);
    xbuf[(size_t)t * E + d] = emb[(size_t)tok * E + d] + pe;
  }
}

template <int K>
__global__ __launch_bounds__(256) void gemm_k(
    const float* __restrict__ x, const float* __restrict__ W, const float* __restrict__ bias,
    int ntok, int nout, int route, int relu,
    float* __restrict__ out0, float* __restrict__ out1, float* __restrict__ out2) {
  constexpr int K4 = K / 4;
  constexpr int J  = K / 256;
  __shared__ float4 xt[8][K4];
  const int tid = threadIdx.x;
  const int lane = tid & 63;
  const int o = blockIdx.x * 4 + (tid >> 6);

  float4 wr[J];
  if (o < nout) {
    const float4* Wr = (const float4*)(W + (size_t)o * K);
#pragma unroll
    for (int j = 0; j < J; ++j) wr[j] = Wr[lane + 64 * j];
  }

  const int ng = ntok >> 3;
  for (int g = 0; g < ng; ++g) {
    if (g) __syncthreads();
    const float4* xg = (const float4*)(x + (size_t)g * 8 * K);
    float4* xf = &xt[0][0];
    for (int i = tid; i < 8 * K4; i += 256) xf[i] = xg[i];
    __syncthreads();
    if (o < nout) {
      float acc[8] = {0, 0, 0, 0, 0, 0, 0, 0};
#pragma unroll
      for (int j = 0; j < J; ++j) {
        float4 w = wr[j];
#pragma unroll
        for (int tt = 0; tt < 8; ++tt) {
          float4 xv = xt[tt][lane + 64 * j];
          acc[tt] += w.x * xv.x + w.y * xv.y + w.z * xv.z + w.w * xv.w;
        }
      }
#pragma unroll
      for (int tt = 0; tt < 8; ++tt) acc[tt] = wsum(acc[tt]);
      if (lane == 0) {
        float bo = bias[o];
#pragma unroll
        for (int tt = 0; tt < 8; ++tt) {
          float v = acc[tt] + bo;
          if (relu) v = fmaxf(v, 0.f);
          int t = g * 8 + tt;
          if (route == 0) {
            out0[(size_t)t * nout + o] = v;
          } else if (route == 1) {
            if (o < E) out0[(size_t)t * E + o] = v;
            else if (o < 2 * E) out1[(size_t)t * E + (o - E)] = v;
            else out2[(size_t)t * E + (o - 2 * E)] = v;
          } else {
            if (o < E) out0[(size_t)t * E + o] = v;
            else out1[(size_t)t * E + (o - E)] = v;
          }
        }
      }
    }
  }
}

__global__ __launch_bounds__(256) void attn_k(
    const float* __restrict__ q, const float* __restrict__ Kc, const float* __restrict__ Vc,
    float* __restrict__ outp, int p0, int nq, int nk_fixed, int causal) {
  const int tid = threadIdx.x;
  const int lane = tid & 63;
  const int u = blockIdx.x * 4 + (tid >> 6);
  if (u >= nq * 64) return;
  const int qi = u >> 6;
  const int r = u & 63;
  const int b = r >> 3, h = r & 7;
  const int nk = causal ? (p0 + qi + 1) : nk_fixed;

  const size_t qoff = (size_t)(qi * B + b) * E + h * DH + lane;
  const float qv = q[qoff];

  float myscore = -INFINITY;
  for (int k = 0; k < nk; ++k) {
    float prod = qv * Kc[(size_t)(k * B + b) * E + h * DH + lane];
    prod = wsum(prod);
    if (lane == k) myscore = prod * 0.125f;
  }
  float m = myscore;
#pragma unroll
  for (int off = 32; off; off >>= 1) m = fmaxf(m, __shfl_xor(m, off));
  float p = (lane < nk) ? expf(myscore - m) : 0.f;
  float denom = wsum(p);
  float a = p / denom;

  float oacc = 0.f;
  for (int k = 0; k < nk; ++k) {
    float ak = __shfl(a, k);
    oacc = fmaf(ak, Vc[(size_t)(k * B + b) * E + h * DH + lane], oacc);
  }
  outp[qoff] = oacc;
}

__global__ __launch_bounds__(256) void add_ln_k(
    const float* __restrict__ xa, const float* __restrict__ xb,
    const float* __restrict__ g, const float* __restrict__ beta,
    float* __restrict__ outp, int ntok) {
  const int tid = threadIdx.x, lane = tid & 63;
  const int t = blockIdx.x * 4 + (tid >> 6);
  if (t >= ntok) return;
  float v[8];
  float s = 0.f;
#pragma unroll
  for (int j = 0; j < 8; ++j) {
    int d = lane + 64 * j;
    v[j] = xa[(size_t)t * E + d] + xb[(size_t)t * E + d];
    s += v[j];
  }
  s = wsum(s);
  float mean = s * (1.f / 512.f);
  float d2 = 0.f;
#pragma unroll
  for (int j = 0; j < 8; ++j) { float dd = v[j] - mean; d2 += dd * dd; }
  d2 = wsum(d2);
  float inv = 1.f / sqrtf(d2 * (1.f / 512.f) + 1e-5f);
#pragma unroll
  for (int j = 0; j < 8; ++j) {
    int d = lane + 64 * j;
    outp[(size_t)t * E + d] = (v[j] - mean) * inv * g[d] + beta[d];
  }
}

// ================= persistent autoregressive decode kernel =================

__global__ __launch_bounds__(NT, 1) void decode_persist_k(
    const float* __restrict__ emb,
    const float* __restrict__ sa_w, const float* __restrict__ sa_b,
    const float* __restrict__ sa_ow, const float* __restrict__ sa_ob,
    const float* __restrict__ ca_w, const float* __restrict__ ca_b,
    const float* __restrict__ ca_ow, const float* __restrict__ ca_ob,
    const float* __restrict__ ff1_w, const float* __restrict__ ff1_b,
    const float* __restrict__ ff2_w, const float* __restrict__ ff2_b,
    const float* __restrict__ ln_g, const float* __restrict__ ln_b,
    const float* __restrict__ out_w, const float* __restrict__ out_b,
    float* __restrict__ kself, float* __restrict__ vself,
    const float* __restrict__ kcross, const float* __restrict__ vcross,
    float* __restrict__ qbuf, float* __restrict__ attnout, float* __restrict__ gout,
    float* __restrict__ xlbuf, float* __restrict__ x1buf, float* __restrict__ x2buf,
    float* __restrict__ xstep, float* __restrict__ ffdec,
    float* __restrict__ outp, int* __restrict__ bar) {
  __shared__ float s_x[8 * FF];        // 64 KB staging tile (max: ff2 K=2048)
  __shared__ float s_red[NT];
  __shared__ int   s_idx[NT];

  const int tid  = threadIdx.x;
  const int lane = tid & 63;
  const int wv   = tid >> 6;
  const int wid  = blockIdx.x * (NT / 64) + wv;
  const size_t SELF_SZ  = (size_t)LF * B * E;
  const size_t CROSS_SZ = (size_t)S * B * E;
  int bt = 0;

  // ---- grid barrier: RELAXED tree (8 groups x 32 + root). __syncthreads()
  // provides the vmcnt(0) drain (our coherent stores are then at the MALL);
  // no acquire/release -> no buffer_inv/wbl2 storms.
  auto bar_sync = [&]() {
    ++bt;
    __syncthreads();
    if (tid == 0) {
      const int g = blockIdx.x & 7;
      int old = __hip_atomic_fetch_add(&bar[g * 32], 1, __ATOMIC_RELAXED, __HIP_MEMORY_SCOPE_AGENT);
      if (old == bt * 32 - 1) {
        int ro = __hip_atomic_fetch_add(&bar[8 * 32], 1, __ATOMIC_RELAXED, __HIP_MEMORY_SCOPE_AGENT);
        if (ro == bt * 8 - 1)
          __hip_atomic_store(&bar[10 * 32], bt, __ATOMIC_RELAXED, __HIP_MEMORY_SCOPE_AGENT);
      }
      while (__hip_atomic_load(&bar[10 * 32], __ATOMIC_RELAXED, __HIP_MEMORY_SCOPE_AGENT) < bt)
        __builtin_amdgcn_s_sleep(8);
    }
    __syncthreads();
    __builtin_amdgcn_sched_barrier(0);
  };

  // ---- stage activation tile [8][K] -> LDS via coherence-point loads ----
  auto stage_copy = [&](const float* src, int nflt) {
    float2* d2 = (float2*)s_x;
    for (int i = tid; i < nflt / 2; i += NT) d2[i] = ldc8(src + 2 * i);
    __syncthreads();
  };
  // s_x[token] = LN(xa+xb)*g+be ; wave wv = token wv; block 0 also materializes to wout
  auto stage_ln = [&](const float* xa, const float* xb, const float* g, const float* be,
                      float* wout) {
    float v[8];
    float s = 0.f;
#pragma unroll
    for (int j = 0; j < 8; ++j) {
      int d = lane + 64 * j;
      v[j] = ldc(&xa[wv * E + d]) + ldc(&xb[wv * E + d]);
      s += v[j];
    }
    s = wsum(s);
    float mean = s * (1.f / 512.f);
    float d2 = 0.f;
#pragma unroll
    for (int j = 0; j < 8; ++j) { float dd = v[j] - mean; d2 += dd * dd; }
    d2 = wsum(d2);
    float inv = 1.f / sqrtf(d2 * (1.f / 512.f) + 1e-5f);
#pragma unroll
    for (int j = 0; j < 8; ++j) {
      int d = lane + 64 * j;
      float nv = (v[j] - mean) * inv * g[d] + be[d];
      s_x[wv * E + d] = nv;
      if (wout && blockIdx.x == 0) stc(&wout[wv * E + d], nv);
    }
    __syncthreads();
  };

  // ---- GEMM over staged tile; weights via NORMAL cached loads (L2-resident),
  // outputs via coherence-point stores ----
  auto gemm = [&](int K, const float* W, const float* bias, int nout, int relu, int route,
                  float* o0, float* kdst, float* vdst) {
    const float4* sx4 = (const float4*)s_x;
    const int K4 = K / 4;
    const int NJ = K / 256;
    for (int o = wid; o < nout; o += NWAVE) {
      const float4* Wr = (const float4*)(W + (size_t)o * K);
      float acc[8] = {0, 0, 0, 0, 0, 0, 0, 0};
      for (int jj = 0; jj < NJ; ++jj) {
        float4 w = Wr[lane + 64 * jj];
#pragma unroll
        for (int t = 0; t < 8; ++t) {
          float4 xv = sx4[t * K4 + lane + 64 * jj];
          acc[t] += w.x * xv.x + w.y * xv.y + w.z * xv.z + w.w * xv.w;
        }
      }
#pragma unroll
      for (int t = 0; t < 8; ++t) acc[t] = wsum(acc[t]);
      if (lane == 0) {
        float bo = bias[o];
#pragma unroll
        for (int t = 0; t < 8; ++t) {
          float vv = acc[t] + bo;
          if (relu) vv = fmaxf(vv, 0.f);
          if (route == 0) stc(&o0[(size_t)t * nout + o], vv);
          else {
            if (o < E) stc(&o0[t * E + o], vv);
            else if (o < 2 * E) stc(&kdst[t * E + (o - E)], vv);
            else stc(&vdst[t * E + (o - 2 * E)], vv);
          }
        }
      }
    }
  };

  // ---- attention: blocks 0..7 = batch, wave = head, lane = dim.
  // K/V via normal cached loads (rows are write-once & line-aligned; index clamp
  // never touches unwritten lines). q via coherent load. KMAX=48 unrolled.
  auto attn = [&](const float* Kc, const float* Vc, int nk) {
    if (blockIdx.x < 8) {
      const int b = blockIdx.x, h = wv;
      const float qv = ldc(&qbuf[b * E + h * DH + lane]);
      float sc[48];
#pragma unroll
      for (int k = 0; k < 48; ++k) {
        int kk = (k < nk) ? k : nk - 1;
        sc[k] = qv * Kc[(size_t)(kk * B + b) * E + h * DH + lane];
      }
#pragma unroll
      for (int k = 0; k < 48; ++k) sc[k] = wsum(sc[k]) * 0.125f;
      float m = -INFINITY;
#pragma unroll
      for (int k = 0; k < 48; ++k) if (k < nk) m = fmaxf(m, sc[k]);
      float den = 0.f;
#pragma unroll
      for (int k = 0; k < 48; ++k) {
        float e = (k < nk) ? expf(sc[k] - m) : 0.f;
        sc[k] = e; den += e;
      }
      float inv = 1.f / den;
      float oa = 0.f;
#pragma unroll
      for (int k = 0; k < 48; ++k) {
        int kk = (k < nk) ? k : nk - 1;
        oa = fmaf(sc[k] * inv, Vc[(size_t)(kk * B + b) * E + h * DH + lane], oa);
      }
      stc(&attnout[b * E + h * DH + lane], oa);
    }
  };

  // ================= 23 autoregressive steps =================
  for (int i = 0; i < MAXLEN - 1; ++i) {
    const int p = INIT + i;                    // position being decoded (12..34)

    // stage 0: argmax of logits row p-1 (per batch) + re-embed at PE position 0
    if (blockIdx.x < 8) {
      const float* row = outp + ((size_t)(p - 1) * B + blockIdx.x) * V;
      float bv = -INFINITY; int bi = 0x7fffffff;
      for (int j = tid; j < V / 2; j += NT) {
        float2 vv = ldc8(row + 2 * j);
        if (vv.x > bv || (vv.x == bv && 2 * j < bi)) { bv = vv.x; bi = 2 * j; }
        if (vv.y > bv || (vv.y == bv && 2 * j + 1 < bi)) { bv = vv.y; bi = 2 * j + 1; }
      }
      s_red[tid] = bv; s_idx[tid] = bi;
      __syncthreads();
      for (int s = NT / 2; s; s >>= 1) {
        if (tid < s) {
          float ov = s_red[tid + s]; int oi = s_idx[tid + s];
          if (ov > s_red[tid] || (ov == s_red[tid] && oi < s_idx[tid])) {
            s_red[tid] = ov; s_idx[tid] = oi;
          }
        }
        __syncthreads();
      }
      const int tok = s_idx[0];
      for (int d = tid; d < E; d += NT)
        stc(&xstep[blockIdx.x * E + d], emb[(size_t)tok * E + d] + ((d & 1) ? 1.0f : 0.0f));
    }
    bar_sync();

    for (int l = 0; l < NL; ++l) {
      // S1: QKV projection (for l=1, fuse layer-0 final LN into staging)
      if (l == 0) stage_copy(xstep, 8 * E);
      else        stage_ln(x2buf, gout, ln_g + 2 * E, ln_b + 2 * E, xlbuf);
      gemm(E, sa_w + (size_t)l * 3 * E * E, sa_b + (size_t)l * 3 * E, 3 * E, 0, 1,
           qbuf, kself + l * SELF_SZ + (size_t)p * B * E, vself + l * SELF_SZ + (size_t)p * B * E);
      bar_sync();
      // S2: self-attention (keys 0..p)
      attn(kself + l * SELF_SZ, vself + l * SELF_SZ, p + 1);
      bar_sync();
      // S3: self-attn output projection
      stage_copy(attnout, 8 * E);
      gemm(E, sa_ow + (size_t)l * E * E, sa_ob + (size_t)l * E, E, 0, 0, gout, 0, 0);
      bar_sync();
      // S4: x1 = LN(x + sa_out); cross-attn Q projection
      stage_ln((l == 0) ? xstep : xlbuf, gout,
               ln_g + ((size_t)l * 3 + 0) * E, ln_b + ((size_t)l * 3 + 0) * E, x1buf);
      gemm(E, ca_w + (size_t)l * 3 * E * E, ca_b + (size_t)l * 3 * E, E, 0, 0, qbuf, 0, 0);
      bar_sync();
      // S5: cross-attention (48 encoder keys)
      attn(kcross + l * CROSS_SZ, vcross + l * CROSS_SZ, S);
      bar_sync();
      // S6: cross-attn output projection
      stage_copy(attnout, 8 * E);
      gemm(E, ca_ow + (size_t)l * E * E, ca_ob + (size_t)l * E, E, 0, 0, gout, 0, 0);
      bar_sync();
      // S7: x2 = LN(x1 + ca_out); FFN-1 (ReLU)
      stage_ln(x1buf, gout, ln_g + ((size_t)l * 3 + 1) * E, ln_b + ((size_t)l * 3 + 1) * E, x2buf);
      gemm(E, ff1_w + (size_t)l * FF * E, ff1_b + (size_t)l * FF, FF, 1, 0, ffdec, 0, 0);
      bar_sync();
      // S8: FFN-2
      stage_copy(ffdec, 8 * FF);
      gemm(FF, ff2_w + (size_t)l * E * FF, ff2_b + (size_t)l * E, E, 0, 0, gout, 0, 0);
      bar_sync();
    }
    // logits: x3 = LN(x2 + ff_out) -> output projection into final rows
    stage_ln(x2buf, gout, ln_g + (3 + 2) * E, ln_b + (3 + 2) * E, nullptr);
    gemm(E, out_w, out_b, V, 0, 0, outp + (size_t)p * B * V, 0, 0);
    bar_sync();
  }
}

extern "C" void kernel_launch(void* const* d_in, const int* in_sizes, int n_in,
                              void* d_out, int out_size, void* d_ws, size_t ws_size,
                              hipStream_t stream) {
  const float* enc       = (const float*)d_in[0];
  const int*   transform = (const int*)d_in[1];
  const float* emb       = (const float*)d_in[3];
  const float* sa_w  = (const float*)d_in[4];
  const float* sa_b  = (const float*)d_in[5];
  const float* sa_ow = (const float*)d_in[6];
  const float* sa_ob = (const float*)d_in[7];
  const float* ca_w  = (const float*)d_in[8];
  const float* ca_b  = (const float*)d_in[9];
  const float* ca_ow = (const float*)d_in[10];
  const float* ca_ob = (const float*)d_in[11];
  const float* ff1_w = (const float*)d_in[12];
  const float* ff1_b = (const float*)d_in[13];
  const float* ff2_w = (const float*)d_in[14];
  const float* ff2_b = (const float*)d_in[15];
  const float* ln_g  = (const float*)d_in[16];
  const float* ln_b  = (const float*)d_in[17];
  const float* out_w = (const float*)d_in[18];
  const float* out_b = (const float*)d_in[19];
  float* out = (float*)d_out;

  // workspace layout (floats)
  const size_t SELF_SZ  = (size_t)LF * B * E;    // 143360
  const size_t CROSS_SZ = (size_t)S * B * E;     // 196608
  float* ws     = (float*)d_ws;
  float* xbuf   = ws;                            // 12 prefill positions
  float* kself  = xbuf + (size_t)INIT * B * E;
  float* vself  = kself + NL * SELF_SZ;
  float* kcross = vself + NL * SELF_SZ;
  float* vcross = kcross + NL * CROSS_SZ;
  float* act0   = vcross + NL * CROSS_SZ;        // [96,E]
  float* act1   = act0 + 96 * E;
  float* act2   = act1 + 96 * E;
  float* act3   = act2 + 96 * E;
  float* ffb    = act3 + 96 * E;                 // [96,FF]
  int*   bar    = (int*)(ffb + 96 * FF);         // 512 ints (tree counters, 128B-spaced)

  hipMemsetAsync(bar, 0, 2048, stream);

  // 1) initial embeddings (positions 0..11)
  embed_init_k<<<INIT * B, 128, 0, stream>>>(transform, emb, xbuf);

  // 2) cross-attn K/V caches
  for (int l = 0; l < NL; ++l) {
    gemm_k<E><<<(2 * E) / 4, 256, 0, stream>>>(
        enc, ca_w + ((size_t)l * 3 * E + E) * E, ca_b + (size_t)l * 3 * E + E,
        S * B, 2 * E, 2, 0, kcross + l * CROSS_SZ, vcross + l * CROSS_SZ, nullptr);
  }

  // 3) prefill positions 0..11 (round-1 kernels, one-time)
  {
    const int p0 = 0, nq = INIT, ntok = nq * B;
    const float* xin = xbuf;
    for (int l = 0; l < NL; ++l) {
      const float* x = (l == 0) ? xin : act0;
      gemm_k<E><<<(3 * E) / 4, 256, 0, stream>>>(
          x, sa_w + (size_t)l * 3 * E * E, sa_b + (size_t)l * 3 * E, ntok, 3 * E, 1, 0,
          act1, kself + l * SELF_SZ, vself + l * SELF_SZ);
      attn_k<<<nq * 16, 256, 0, stream>>>(act1, kself + l * SELF_SZ, vself + l * SELF_SZ,
                                          act2, p0, nq, 0, 1);
      gemm_k<E><<<E / 4, 256, 0, stream>>>(
          act2, sa_ow + (size_t)l * E * E, sa_ob + (size_t)l * E, ntok, E, 0, 0, act3, nullptr, nullptr);
      add_ln_k<<<(ntok + 3) / 4, 256, 0, stream>>>(
          x, act3, ln_g + (size_t)l * 3 * E, ln_b + (size_t)l * 3 * E, act0, ntok);
      gemm_k<E><<<E / 4, 256, 0, stream>>>(
          act0, ca_w + (size_t)l * 3 * E * E, ca_b + (size_t)l * 3 * E, ntok, E, 0, 0, act1, nullptr, nullptr);
      attn_k<<<nq * 16, 256, 0, stream>>>(act1, kcross + l * CROSS_SZ, vcross + l * CROSS_SZ,
                                          act2, p0, nq, S, 0);
      gemm_k<E><<<E / 4, 256, 0, stream>>>(
          act2, ca_ow + (size_t)l * E * E, ca_ob + (size_t)l * E, ntok, E, 0, 0, act3, nullptr, nullptr);
      add_ln_k<<<(ntok + 3) / 4, 256, 0, stream>>>(
          act0, act3, ln_g + (size_t)l * 3 * E + E, ln_b + (size_t)l * 3 * E + E, act0, ntok);
      gemm_k<E><<<FF / 4, 256, 0, stream>>>(
          act0, ff1_w + (size_t)l * FF * E, ff1_b + (size_t)l * FF, ntok, FF, 0, 1, ffb, nullptr, nullptr);
      gemm_k<FF><<<E / 4, 256, 0, stream>>>(
          ffb, ff2_w + (size_t)l * E * FF, ff2_b + (size_t)l * E, ntok, E, 0, 0, act3, nullptr, nullptr);
      add_ln_k<<<(ntok + 3) / 4, 256, 0, stream>>>(
          act0, act3, ln_g + (size_t)l * 3 * E + 2 * E, ln_b + (size_t)l * 3 * E + 2 * E, act0, ntok);
    }
    gemm_k<E><<<V / 4, 256, 0, stream>>>(
        act0, out_w, out_b, ntok, V, 0, 0, out, nullptr, nullptr);
  }

  // 4) persistent kernel: all 23 autoregressive steps
  float* qbuf    = act1;
  float* attnout = act2;
  float* gout    = act3;
  float* xlbuf   = act0;
  float* x1buf   = act0 + 8 * E;
  float* x2buf   = act0 + 16 * E;
  float* xstep   = act0 + 24 * E;
  float* ffdec   = ffb;            // [8,2048]
  decode_persist_k<<<NB, NT, 0, stream>>>(
      emb, sa_w, sa_b, sa_ow, sa_ob, ca_w, ca_b, ca_ow, ca_ob,
      ff1_w, ff1_b, ff2_w, ff2_b, ln_g, ln_b, out_w, out_b,
      kself, vself, kcross, vcross,
      qbuf, attnout, gout, xlbuf, x1buf, x2buf, xstep, ffdec,
      out, bar);
}